// Round 1
// baseline (135.146 us; speedup 1.0000x reference)
//
#include <hip/hip_runtime.h>
#include <math.h>

#define NSAMP 100

__device__ __forceinline__ float fast_sigmoid(float x) {
    // sigmoid(x) = 1 / (1 + e^-x);  e^-x = 2^(-x*log2(e))
    float e = __builtin_amdgcn_exp2f(-1.44269504088896f * x);
    return __builtin_amdgcn_rcpf(1.0f + e);
}

__device__ __forceinline__ float wave_reduce_sum(float v) {
    #pragma unroll
    for (int off = 32; off > 0; off >>= 1)
        v += __shfl_down(v, off, 64);
    return v;
}

__global__ __launch_bounds__(256) void stoch_loss_rows(
    const float* __restrict__ logits,
    const float* __restrict__ stddevs,
    const float* __restrict__ targets,
    const float* __restrict__ noise,
    float* __restrict__ partial,
    int n)
{
    const int row = blockIdx.x * 256 + threadIdx.x;
    float loss = 0.0f;
    if (row < n) {
        const float lg = logits[row];
        const float sd = stddevs[row];
        const float tg = targets[row];
        const float4* nz = reinterpret_cast<const float4*>(noise + (size_t)row * NSAMP);
        float acc = 0.0f;
        #pragma unroll
        for (int j = 0; j < NSAMP / 4; ++j) {
            float4 v = nz[j];
            acc += fast_sigmoid(fmaf(sd, v.x, lg));
            acc += fast_sigmoid(fmaf(sd, v.y, lg));
            acc += fast_sigmoid(fmaf(sd, v.z, lg));
            acc += fast_sigmoid(fmaf(sd, v.w, lg));
        }
        const float p = acc * (1.0f / NSAMP);
        const float log_p   = fmaxf(__logf(p), -100.0f);
        const float log_1mp = fmaxf(log1pf(-p), -100.0f);
        loss = -(tg * log_p + (1.0f - tg) * log_1mp);
    }
    // block reduction: wave shuffle, then 4 wave sums via LDS
    float wsum = wave_reduce_sum(loss);
    __shared__ float lds[4];
    const int wid  = threadIdx.x >> 6;
    const int lane = threadIdx.x & 63;
    if (lane == 0) lds[wid] = wsum;
    __syncthreads();
    if (threadIdx.x == 0)
        partial[blockIdx.x] = (lds[0] + lds[1]) + (lds[2] + lds[3]);
}

__global__ __launch_bounds__(256) void reduce_partial(
    const float* __restrict__ partial, float* __restrict__ out,
    int nparts, float scale)
{
    float s = 0.0f;
    for (int i = threadIdx.x; i < nparts; i += 256)
        s += partial[i];
    float wsum = wave_reduce_sum(s);
    __shared__ float lds[4];
    const int wid  = threadIdx.x >> 6;
    const int lane = threadIdx.x & 63;
    if (lane == 0) lds[wid] = wsum;
    __syncthreads();
    if (threadIdx.x == 0)
        out[0] = ((lds[0] + lds[1]) + (lds[2] + lds[3])) * scale;
}

extern "C" void kernel_launch(void* const* d_in, const int* in_sizes, int n_in,
                              void* d_out, int out_size, void* d_ws, size_t ws_size,
                              hipStream_t stream) {
    const float* logits  = (const float*)d_in[0];
    const float* stddevs = (const float*)d_in[1];
    const float* targets = (const float*)d_in[2];
    const float* noise   = (const float*)d_in[3];
    float* out = (float*)d_out;

    const int n = in_sizes[0];
    const int nblocks = (n + 255) / 256;
    float* partial = (float*)d_ws;   // nblocks floats, written before read

    stoch_loss_rows<<<nblocks, 256, 0, stream>>>(logits, stddevs, targets, noise,
                                                 partial, n);
    reduce_partial<<<1, 256, 0, stream>>>(partial, out, nblocks, 1.0f / (float)n);
}

// Round 2
// 91.039 us; speedup vs baseline: 1.4845x; 1.4845x over previous
//
#include <hip/hip_runtime.h>
#include <math.h>

#define NSAMP 100
#define F4_PER_ROW 25                 // 100 floats = 25 float4
#define ROWS_PER_BLOCK 256
#define F4_PER_BLOCK (ROWS_PER_BLOCK * F4_PER_ROW)   // 6400

__device__ __forceinline__ float fast_sigmoid(float x) {
    float e = __builtin_amdgcn_exp2f(-1.44269504088896f * x);
    return __builtin_amdgcn_rcpf(1.0f + e);
}

__device__ __forceinline__ float wave_reduce_sum(float v) {
    #pragma unroll
    for (int off = 32; off > 0; off >>= 1)
        v += __shfl_down(v, off, 64);
    return v;
}

__global__ __launch_bounds__(256) void stoch_loss_rows(
    const float* __restrict__ logits,
    const float* __restrict__ stddevs,
    const float* __restrict__ targets,
    const float* __restrict__ noise,
    float* __restrict__ partial,
    int n)
{
    __shared__ float s_lg[ROWS_PER_BLOCK];
    __shared__ float s_sd[ROWS_PER_BLOCK];
    __shared__ float s_part[F4_PER_BLOCK];   // 25.6 KB per-float4 partial sums
    __shared__ float s_red[4];

    const int tid = threadIdx.x;
    const int r0  = blockIdx.x * ROWS_PER_BLOCK;
    const int r   = r0 + tid;
    const bool valid_row = (r < n);

    s_lg[tid] = valid_row ? logits[r]  : 0.0f;
    s_sd[tid] = valid_row ? stddevs[r] : 0.0f;
    __syncthreads();

    // Coalesced pass over this block's 6400 contiguous float4s of noise.
    const float4* nz = reinterpret_cast<const float4*>(noise);
    const size_t base = (size_t)blockIdx.x * F4_PER_BLOCK;
    const size_t f4_limit = (size_t)n * F4_PER_ROW;
    #pragma unroll
    for (int i = 0; i < F4_PER_ROW; ++i) {
        const int f_local = i * 256 + tid;       // 0..6399
        const int rl = f_local / F4_PER_ROW;     // local row of this float4
        const size_t f = base + f_local;
        float acc = 0.0f;
        if (f < f4_limit) {
            const float4 v = nz[f];
            const float lg = s_lg[rl];
            const float sd = s_sd[rl];
            acc  = fast_sigmoid(fmaf(sd, v.x, lg));
            acc += fast_sigmoid(fmaf(sd, v.y, lg));
            acc += fast_sigmoid(fmaf(sd, v.z, lg));
            acc += fast_sigmoid(fmaf(sd, v.w, lg));
        }
        s_part[f_local] = acc;
    }
    __syncthreads();

    // Per-row reduce: thread t sums its row's 25 partials (stride-25 -> 2-way
    // bank alias, free), then BCE.
    float loss = 0.0f;
    if (valid_row) {
        float acc = 0.0f;
        #pragma unroll
        for (int j = 0; j < F4_PER_ROW; ++j)
            acc += s_part[tid * F4_PER_ROW + j];
        const float p = acc * (1.0f / NSAMP);
        const float tg = targets[r];
        const float log_p   = fmaxf(__logf(p), -100.0f);
        const float log_1mp = fmaxf(log1pf(-p), -100.0f);
        loss = -(tg * log_p + (1.0f - tg) * log_1mp);
    }

    float wsum = wave_reduce_sum(loss);
    const int wid  = tid >> 6;
    const int lane = tid & 63;
    if (lane == 0) s_red[wid] = wsum;
    __syncthreads();
    if (tid == 0)
        partial[blockIdx.x] = (s_red[0] + s_red[1]) + (s_red[2] + s_red[3]);
}

__global__ __launch_bounds__(256) void reduce_partial(
    const float* __restrict__ partial, float* __restrict__ out,
    int nparts, float scale)
{
    float s = 0.0f;
    for (int i = threadIdx.x; i < nparts; i += 256)
        s += partial[i];
    float wsum = wave_reduce_sum(s);
    __shared__ float lds[4];
    const int wid  = threadIdx.x >> 6;
    const int lane = threadIdx.x & 63;
    if (lane == 0) lds[wid] = wsum;
    __syncthreads();
    if (threadIdx.x == 0)
        out[0] = ((lds[0] + lds[1]) + (lds[2] + lds[3])) * scale;
}

extern "C" void kernel_launch(void* const* d_in, const int* in_sizes, int n_in,
                              void* d_out, int out_size, void* d_ws, size_t ws_size,
                              hipStream_t stream) {
    const float* logits  = (const float*)d_in[0];
    const float* stddevs = (const float*)d_in[1];
    const float* targets = (const float*)d_in[2];
    const float* noise   = (const float*)d_in[3];
    float* out = (float*)d_out;

    const int n = in_sizes[0];
    const int nblocks = (n + ROWS_PER_BLOCK - 1) / ROWS_PER_BLOCK;
    float* partial = (float*)d_ws;

    stoch_loss_rows<<<nblocks, 256, 0, stream>>>(logits, stddevs, targets, noise,
                                                 partial, n);
    reduce_partial<<<1, 256, 0, stream>>>(partial, out, nblocks, 1.0f / (float)n);
}

// Round 4
// 71.480 us; speedup vs baseline: 1.8907x; 1.2736x over previous
//
#include <hip/hip_runtime.h>
#include <math.h>

#define NSAMP 100
#define F4_PER_ROW 25
#define ROWS_PER_BLOCK 256
#define F4_PER_BLOCK (ROWS_PER_BLOCK * F4_PER_ROW)   // 6400

typedef float vfloat4 __attribute__((ext_vector_type(4)));

__device__ __forceinline__ float fast_sigmoid(float x) {
    float e = __builtin_amdgcn_exp2f(-1.44269504088896f * x);
    return __builtin_amdgcn_rcpf(1.0f + e);
}

__device__ __forceinline__ float wave_reduce_sum(float v) {
    #pragma unroll
    for (int off = 32; off > 0; off >>= 1)
        v += __shfl_down(v, off, 64);
    return v;
}

__global__ __launch_bounds__(256) void stoch_loss_rows(
    const float* __restrict__ logits,
    const float* __restrict__ stddevs,
    const float* __restrict__ targets,
    const float* __restrict__ noise,
    float* __restrict__ partial,
    int n)
{
    __shared__ float s_lg[ROWS_PER_BLOCK];
    __shared__ float s_sd[ROWS_PER_BLOCK];
    __shared__ float s_part[F4_PER_BLOCK];
    __shared__ float s_red[4];

    const int tid = threadIdx.x;
    const int r0  = blockIdx.x * ROWS_PER_BLOCK;
    const int r   = r0 + tid;
    const bool valid_row = (r < n);

    s_lg[tid] = valid_row ? logits[r]  : 0.0f;
    s_sd[tid] = valid_row ? stddevs[r] : 0.0f;
    const float tg = valid_row ? targets[r] : 0.0f;   // load early, use late
    __syncthreads();

    const vfloat4* nz = reinterpret_cast<const vfloat4*>(noise);
    const size_t base = (size_t)blockIdx.x * F4_PER_BLOCK;

    if (r0 + ROWS_PER_BLOCK <= n) {
        // Fast path: interior block, no bounds checks. Nontemporal stream:
        // noise is 400 MB single-use (> L3), don't cache it.
        #pragma unroll
        for (int i = 0; i < F4_PER_ROW; ++i) {
            const int f_local = i * 256 + tid;
            const int rl = f_local / F4_PER_ROW;
            const vfloat4 v = __builtin_nontemporal_load(&nz[base + f_local]);
            const float lg = s_lg[rl];
            const float sd = s_sd[rl];
            float acc;
            acc  = fast_sigmoid(fmaf(sd, v.x, lg));
            acc += fast_sigmoid(fmaf(sd, v.y, lg));
            acc += fast_sigmoid(fmaf(sd, v.z, lg));
            acc += fast_sigmoid(fmaf(sd, v.w, lg));
            s_part[f_local] = acc;
        }
    } else {
        const size_t f4_limit = (size_t)n * F4_PER_ROW;
        #pragma unroll
        for (int i = 0; i < F4_PER_ROW; ++i) {
            const int f_local = i * 256 + tid;
            const int rl = f_local / F4_PER_ROW;
            const size_t f = base + f_local;
            float acc = 0.0f;
            if (f < f4_limit) {
                const vfloat4 v = __builtin_nontemporal_load(&nz[f]);
                const float lg = s_lg[rl];
                const float sd = s_sd[rl];
                acc  = fast_sigmoid(fmaf(sd, v.x, lg));
                acc += fast_sigmoid(fmaf(sd, v.y, lg));
                acc += fast_sigmoid(fmaf(sd, v.z, lg));
                acc += fast_sigmoid(fmaf(sd, v.w, lg));
            }
            s_part[f_local] = acc;
        }
    }
    __syncthreads();

    float loss = 0.0f;
    if (valid_row) {
        float acc = 0.0f;
        #pragma unroll
        for (int j = 0; j < F4_PER_ROW; ++j)
            acc += s_part[tid * F4_PER_ROW + j];
        const float p = acc * (1.0f / NSAMP);
        const float log_p   = fmaxf(__logf(p), -100.0f);
        const float log_1mp = fmaxf(log1pf(-p), -100.0f);
        loss = -(tg * log_p + (1.0f - tg) * log_1mp);
    }

    float wsum = wave_reduce_sum(loss);
    const int wid  = tid >> 6;
    const int lane = tid & 63;
    if (lane == 0) s_red[wid] = wsum;
    __syncthreads();
    if (tid == 0)
        partial[blockIdx.x] = (s_red[0] + s_red[1]) + (s_red[2] + s_red[3]);
}

__global__ __launch_bounds__(256) void reduce_partial(
    const float* __restrict__ partial, float* __restrict__ out,
    int nparts, float scale)
{
    float s = 0.0f;
    for (int i = threadIdx.x; i < nparts; i += 256)
        s += partial[i];
    float wsum = wave_reduce_sum(s);
    __shared__ float lds[4];
    const int wid  = threadIdx.x >> 6;
    const int lane = threadIdx.x & 63;
    if (lane == 0) lds[wid] = wsum;
    __syncthreads();
    if (threadIdx.x == 0)
        out[0] = ((lds[0] + lds[1]) + (lds[2] + lds[3])) * scale;
}

extern "C" void kernel_launch(void* const* d_in, const int* in_sizes, int n_in,
                              void* d_out, int out_size, void* d_ws, size_t ws_size,
                              hipStream_t stream) {
    const float* logits  = (const float*)d_in[0];
    const float* stddevs = (const float*)d_in[1];
    const float* targets = (const float*)d_in[2];
    const float* noise   = (const float*)d_in[3];
    float* out = (float*)d_out;

    const int n = in_sizes[0];
    const int nblocks = (n + ROWS_PER_BLOCK - 1) / ROWS_PER_BLOCK;
    float* partial = (float*)d_ws;

    stoch_loss_rows<<<nblocks, 256, 0, stream>>>(logits, stddevs, targets, noise,
                                                 partial, n);
    reduce_partial<<<1, 256, 0, stream>>>(partial, out, nblocks, 1.0f / (float)n);
}